// Round 12
// baseline (103.263 us; speedup 1.0000x reference)
//
#include <hip/hip_runtime.h>
#include <hip/hip_bf16.h>

// Block-diagonal matmul: out[t, n*64+e] = sum_d inp[t, n*64+d] * blocks[n, d, e]
// T=16384, 64 blocks of 64x64, fp32 in/out, bf16 MFMA compute.
//
// Round 12: R11 (101.7us, WRITE=output exactly, 4.0 TB/s eff) + L3 residency
// control. FETCH has been pinned at 135.7MB (=50% of input) in EVERY kernel:
// the 268MB input cyclically re-scanned through the 256MB L3 gets ~50% hit.
// Split-stream fix: slabs 0..23 (201MB) load normally -> L3-resident across
// replays; slabs 24..31 (67MB) load NON-TEMPORAL (no LLC allocate) -> always
// miss but never evict the resident slice. Predicted FETCH -> ~70-90MB.
// Rest identical to R11: 512-thr WGs, 4-block col group x 512 rows, 16 tiles,
// XOR-swizzled LDS bounce both directions, NT 1KB-contiguous stores.

typedef __attribute__((ext_vector_type(8))) short short8;   // 8 bf16
typedef __attribute__((ext_vector_type(4))) short bf16x4;   // 4 bf16
typedef __attribute__((ext_vector_type(4))) float f32x4;

#define D_TOT  4096
#define TROWS  32
#define NTILES 16
#define RESIDENT_SLABS 24    // slabs 0..23 resident (201MB < 256MB L3), rest streamed

__device__ __forceinline__ short f2b(float x) {
    union { __hip_bfloat16 h; short s; } u;
    u.h = __float2bfloat16(x);
    return u.s;
}

template<bool NT>
__device__ __forceinline__ f32x4 ldg(const float* p) {
    if constexpr (NT) return __builtin_nontemporal_load((const f32x4*)p);
    else              return *(const f32x4*)p;
}

template<bool NT>
__device__ __forceinline__ void run(
    const float* __restrict__ gin, float* __restrict__ gout,
    unsigned char* INB, unsigned char* OUTB,
    const int w, const int lane, const int g, const int lr,
    const int rg, const int b, const short8 (&wf)[4][2])
{
    // ---- prologue: load + stage tile 0 (wave w: rows w, w+8, w+16, w+24) ----
    f32x4 pf[4];
    #pragma unroll
    for (int j = 0; j < 4; ++j)
        pf[j] = ldg<NT>(gin + (size_t)(w + 8 * j) * D_TOT + lane * 4);
    #pragma unroll
    for (int j = 0; j < 4; ++j) {
        const int r = w + 8 * j;
        bf16x4 v;
        v[0] = f2b(pf[j][0]); v[1] = f2b(pf[j][1]);
        v[2] = f2b(pf[j][2]); v[3] = f2b(pf[j][3]);
        *(bf16x4*)&INB[r * 512 + (((lane >> 1) ^ (r & 7)) << 4) + ((lane & 1) << 3)] = v;
    }

    for (int t = 0; t < NTILES; ++t) {
        __syncthreads();   // INB(t) ready; OUTB(t-1) fully consumed

        // ---- compute: b-frags from swizzled INB, 8 MFMA -> acc[4] ----
        const int r = rg * 16 + lr;
        short8 bfrag[2];
        #pragma unroll
        for (int s = 0; s < 2; ++s) {
            const int c = b * 8 + s * 4 + g;      // 16B chunk within row
            bfrag[s] = *(const short8*)&INB[r * 512 + ((c ^ (r & 7)) << 4)];
        }
        f32x4 acc[4];
        #pragma unroll
        for (int nt = 0; nt < 4; ++nt) {
            acc[nt] = (f32x4){0.f, 0.f, 0.f, 0.f};
            acc[nt] = __builtin_amdgcn_mfma_f32_16x16x32_bf16(wf[nt][0], bfrag[0], acc[nt], 0, 0, 0);
            acc[nt] = __builtin_amdgcn_mfma_f32_16x16x32_bf16(wf[nt][1], bfrag[1], acc[nt], 0, 0, 0);
        }

        // ---- prefetch tile t+1 (1KB-per-row contiguous instructions) ----
        if (t + 1 < NTILES) {
            const float* gi = gin + (size_t)(t + 1) * TROWS * D_TOT;
            #pragma unroll
            for (int j = 0; j < 4; ++j)
                pf[j] = ldg<NT>(gi + (size_t)(w + 8 * j) * D_TOT + lane * 4);
        }

        // ---- acc -> swizzled OUTB ----
        #pragma unroll
        for (int nt = 0; nt < 4; ++nt) {
            const int c = b * 16 + nt * 4 + g;    // 16B chunk 0..63
            *(f32x4*)&OUTB[r * 1024 + ((c ^ (r & 7)) << 4)] = acc[nt];
        }

        __syncthreads();   // OUTB(t) complete; INB(t) free

        // ---- store OUTB row-linear, NT, 1KB/instr + stage INB(t+1) ----
        float* go = gout + (size_t)t * TROWS * D_TOT;
        #pragma unroll
        for (int j = 0; j < 4; ++j) {
            const int r2 = w + 8 * j;
            f32x4 v = *(const f32x4*)&OUTB[r2 * 1024 + ((lane ^ (r2 & 7)) << 4)];
            __builtin_nontemporal_store(v, (f32x4*)(go + (size_t)r2 * D_TOT + lane * 4));
        }
        if (t + 1 < NTILES) {
            #pragma unroll
            for (int j = 0; j < 4; ++j) {
                const int r2 = w + 8 * j;
                bf16x4 v;
                v[0] = f2b(pf[j][0]); v[1] = f2b(pf[j][1]);
                v[2] = f2b(pf[j][2]); v[3] = f2b(pf[j][3]);
                *(bf16x4*)&INB[r2 * 512 + (((lane >> 1) ^ (r2 & 7)) << 4) + ((lane & 1) << 3)] = v;
            }
        }
    }
}

__global__ __launch_bounds__(512, 2) void block_linear_kernel(
    const float* __restrict__ inp,
    const float* __restrict__ blocks,
    float* __restrict__ out)
{
    __shared__ __align__(16) unsigned char INB[TROWS * 512];    // bf16 [32][256], swizzled
    __shared__ __align__(16) unsigned char OUTB[TROWS * 1024];  // f32  [32][256], swizzled

    const int slab = blockIdx.x;        // 0..31 : 512-row slab
    const int ngrp = blockIdx.y;        // 0..15 : group of 4 consecutive blocks
    const int tid  = threadIdx.x;
    const int w    = tid >> 6;          // wave 0..7
    const int lane = tid & 63;
    const int g    = lane >> 4;         // k-group
    const int lr   = lane & 15;
    const int rg   = w >> 2;            // row-half (rows rg*16 + lr)
    const int b    = w & 3;             // block within group

    // ---- weights for block ngrp*4+b -> frag registers (one-time, L3-hot) ----
    // frag (nt,s): lane (g,lr) holds W[d = s*32+8g+i][e = nt*16+lr], i=0..7
    const float* Wn = blocks + (size_t)(ngrp * 4 + b) * 4096;
    short8 wf[4][2];
    #pragma unroll
    for (int nt = 0; nt < 4; ++nt)
        #pragma unroll
        for (int s = 0; s < 2; ++s) {
            short8 a;
            #pragma unroll
            for (int i = 0; i < 8; ++i)
                a[i] = f2b(Wn[(s * 32 + 8 * g + i) * 64 + nt * 16 + lr]);
            wf[nt][s] = a;
        }

    const float* gin  = inp + (size_t)slab * 512 * D_TOT + ngrp * 256;
    float*       gout = out + (size_t)slab * 512 * D_TOT + ngrp * 256;

    if (slab < RESIDENT_SLABS)
        run<false>(gin, gout, INB, OUTB, w, lane, g, lr, rg, b, wf);
    else
        run<true >(gin, gout, INB, OUTB, w, lane, g, lr, rg, b, wf);
}

extern "C" void kernel_launch(void* const* d_in, const int* in_sizes, int n_in,
                              void* d_out, int out_size, void* d_ws, size_t ws_size,
                              hipStream_t stream) {
    const float* inp    = (const float*)d_in[0];
    const float* blocks = (const float*)d_in[1];
    float* out          = (float*)d_out;

    dim3 grid(32, 16);   // 32 row-slabs x 16 block-groups = 512 WGs (2/CU exact)
    block_linear_kernel<<<grid, 512, 0, stream>>>(inp, blocks, out);
}

// Round 13
// 100.838 us; speedup vs baseline: 1.0241x; 1.0241x over previous
//
#include <hip/hip_runtime.h>
#include <hip/hip_bf16.h>

// Block-diagonal matmul: out[t, n*64+e] = sum_d inp[t, n*64+d] * blocks[n, d, e]
// T=16384, 64 blocks of 64x64, fp32 in/out, bf16 MFMA compute.
//
// Round 13: R11 mechanics (1KB-contiguous bursts both ways, XOR-swizzled LDS
// bounce, NT full-line stores, WRITE=output exactly) at DOUBLE occupancy.
//  - TROWS=16 -> LDS 24KB -> 4 WGs/CU (32 waves, vs R11's 2 WGs/35% occ).
//  - grid 1024 = 64 slabs x 16 ngrps, 512 thr, single uniform round.
//  - wave w: block b = w&3, col-half h = w>>2 (nt in {2h, 2h+1}); weights 16
//    VGPRs, acc 8 -> fits __launch_bounds__(512,8) 64-VGPR cap.
//  - R12's NT loads were neutral -> normal loads (keep L3 hits).

typedef __attribute__((ext_vector_type(8))) short short8;   // 8 bf16
typedef __attribute__((ext_vector_type(4))) short bf16x4;   // 4 bf16
typedef __attribute__((ext_vector_type(4))) float f32x4;

#define D_TOT  4096
#define TROWS  16
#define NTILES 16          // 256 rows per WG

__device__ __forceinline__ short f2b(float x) {
    union { __hip_bfloat16 h; short s; } u;
    u.h = __float2bfloat16(x);
    return u.s;
}

__global__ __launch_bounds__(512, 8) void block_linear_kernel(
    const float* __restrict__ inp,
    const float* __restrict__ blocks,
    float* __restrict__ out)
{
    __shared__ __align__(16) unsigned char INB[TROWS * 512];    // bf16 [16][256], swizzled
    __shared__ __align__(16) unsigned char OUTB[TROWS * 1024];  // f32  [16][256], swizzled

    const int slab = blockIdx.x;        // 0..63 : 256-row slab
    const int ngrp = blockIdx.y;        // 0..15 : group of 4 consecutive blocks
    const int tid  = threadIdx.x;
    const int w    = tid >> 6;          // wave 0..7
    const int lane = tid & 63;
    const int g    = lane >> 4;         // k-group
    const int lr   = lane & 15;
    const int b    = w & 3;             // block within group
    const int h    = w >> 2;            // col-half: nt in {2h, 2h+1}

    // ---- weights for block ngrp*4+b, col-half h -> 16 VGPRs (one-time) ----
    // frag (m,s): lane (g,lr) holds W[d = s*32+8g+i][e = (2h+m)*16+lr], i=0..7
    const float* Wn = blocks + (size_t)(ngrp * 4 + b) * 4096;
    short8 wf[2][2];
    #pragma unroll
    for (int m = 0; m < 2; ++m)
        #pragma unroll
        for (int s = 0; s < 2; ++s) {
            short8 a;
            #pragma unroll
            for (int i = 0; i < 8; ++i)
                a[i] = f2b(Wn[(s * 32 + 8 * g + i) * 64 + (2 * h + m) * 16 + lr]);
            wf[m][s] = a;
        }

    const float* gin  = inp + (size_t)slab * 256 * D_TOT + ngrp * 256;
    float*       gout = out + (size_t)slab * 256 * D_TOT + ngrp * 256;

    // ---- prologue: load + stage tile 0 (wave w: rows w, w+8) ----
    f32x4 pf[2];
    #pragma unroll
    for (int j = 0; j < 2; ++j)
        pf[j] = *(const f32x4*)(gin + (size_t)(w + 8 * j) * D_TOT + lane * 4);
    #pragma unroll
    for (int j = 0; j < 2; ++j) {
        const int r = w + 8 * j;
        bf16x4 v;
        v[0] = f2b(pf[j][0]); v[1] = f2b(pf[j][1]);
        v[2] = f2b(pf[j][2]); v[3] = f2b(pf[j][3]);
        *(bf16x4*)&INB[r * 512 + (((lane >> 1) ^ (r & 7)) << 4) + ((lane & 1) << 3)] = v;
    }

    for (int t = 0; t < NTILES; ++t) {
        __syncthreads();   // INB(t) ready; OUTB(t-1) fully consumed

        // ---- compute: b-frags from swizzled INB (r = lr), 4 MFMA -> acc[2] ----
        const int r = lr;
        short8 bfrag[2];
        #pragma unroll
        for (int s = 0; s < 2; ++s) {
            const int c = b * 8 + s * 4 + g;      // 16B chunk within row
            bfrag[s] = *(const short8*)&INB[r * 512 + ((c ^ (r & 7)) << 4)];
        }
        f32x4 acc[2];
        #pragma unroll
        for (int m = 0; m < 2; ++m) {
            acc[m] = (f32x4){0.f, 0.f, 0.f, 0.f};
            acc[m] = __builtin_amdgcn_mfma_f32_16x16x32_bf16(wf[m][0], bfrag[0], acc[m], 0, 0, 0);
            acc[m] = __builtin_amdgcn_mfma_f32_16x16x32_bf16(wf[m][1], bfrag[1], acc[m], 0, 0, 0);
        }

        // ---- prefetch tile t+1 (1KB-per-row contiguous instructions) ----
        if (t + 1 < NTILES) {
            const float* gi = gin + (size_t)(t + 1) * TROWS * D_TOT;
            #pragma unroll
            for (int j = 0; j < 2; ++j)
                pf[j] = *(const f32x4*)(gi + (size_t)(w + 8 * j) * D_TOT + lane * 4);
        }

        // ---- acc -> swizzled OUTB ----
        #pragma unroll
        for (int m = 0; m < 2; ++m) {
            const int c = b * 16 + (2 * h + m) * 4 + g;   // 16B chunk 0..63
            *(f32x4*)&OUTB[r * 1024 + ((c ^ (r & 7)) << 4)] = acc[m];
        }

        __syncthreads();   // OUTB(t) complete; INB(t) free

        // ---- store OUTB row-linear, NT, 1KB/instr + stage INB(t+1) ----
        float* go = gout + (size_t)t * TROWS * D_TOT;
        #pragma unroll
        for (int j = 0; j < 2; ++j) {
            const int r2 = w + 8 * j;
            f32x4 v = *(const f32x4*)&OUTB[r2 * 1024 + ((lane ^ (r2 & 7)) << 4)];
            __builtin_nontemporal_store(v, (f32x4*)(go + (size_t)r2 * D_TOT + lane * 4));
        }
        if (t + 1 < NTILES) {
            #pragma unroll
            for (int j = 0; j < 2; ++j) {
                const int r2 = w + 8 * j;
                bf16x4 v;
                v[0] = f2b(pf[j][0]); v[1] = f2b(pf[j][1]);
                v[2] = f2b(pf[j][2]); v[3] = f2b(pf[j][3]);
                *(bf16x4*)&INB[r2 * 512 + (((lane >> 1) ^ (r2 & 7)) << 4) + ((lane & 1) << 3)] = v;
            }
        }
    }
}

extern "C" void kernel_launch(void* const* d_in, const int* in_sizes, int n_in,
                              void* d_out, int out_size, void* d_ws, size_t ws_size,
                              hipStream_t stream) {
    const float* inp    = (const float*)d_in[0];
    const float* blocks = (const float*)d_in[1];
    float* out          = (float*)d_out;

    dim3 grid(64, 16);   // 64 row-slabs x 16 block-groups = 1024 WGs (4/CU exact)
    block_linear_kernel<<<grid, 512, 0, stream>>>(inp, blocks, out);
}

// Round 14
// 90.476 us; speedup vs baseline: 1.1413x; 1.1145x over previous
//
#include <hip/hip_runtime.h>
#include <hip/hip_bf16.h>

// Block-diagonal matmul: out[t, n*64+e] = sum_d inp[t, n*64+d] * blocks[n, d, e]
// T=16384, 64 blocks of 64x64, fp32 in/out, bf16 MFMA compute.
//
// Round 14: R13 mechanics (1KB-contiguous bursts, XOR-swizzled LDS transpose
// bounce both ways, NT full-line stores) with DOUBLE-BUFFERED INB+OUTB ->
// ONE barrier per 16-row tile (R13 paid two). Schedule per tile t:
//   issue loads(t+1) -> store OUTB[prev]=tile t-1 -> compute(t)->OUTB[cur]
//   -> stage INB[next] -> barrier.
// Load latency hides under store+compute; tile t-1's store overlaps tile t's
// compute. Grid 32x16 = 512 WGs = exactly 2/CU, uniform; 32 tiles/WG.

typedef __attribute__((ext_vector_type(8))) short short8;   // 8 bf16
typedef __attribute__((ext_vector_type(4))) short bf16x4;   // 4 bf16
typedef __attribute__((ext_vector_type(4))) float f32x4;

#define D_TOT  4096
#define TROWS  16
#define NTILES 32          // 512 rows per WG

__device__ __forceinline__ short f2b(float x) {
    union { __hip_bfloat16 h; short s; } u;
    u.h = __float2bfloat16(x);
    return u.s;
}

__global__ __launch_bounds__(512, 4) void block_linear_kernel(
    const float* __restrict__ inp,
    const float* __restrict__ blocks,
    float* __restrict__ out)
{
    // double-buffered: INB 2x8KB (bf16 [16][256] swz), OUTB 2x16KB (f32 [16][256] swz)
    __shared__ __align__(16) unsigned char INB[2][TROWS * 512];
    __shared__ __align__(16) unsigned char OUTB[2][TROWS * 1024];

    const int slab = blockIdx.x;        // 0..31 : 512-row slab
    const int ngrp = blockIdx.y;        // 0..15 : group of 4 consecutive blocks
    const int tid  = threadIdx.x;
    const int w    = tid >> 6;          // wave 0..7
    const int lane = tid & 63;
    const int g    = lane >> 4;         // k-group
    const int lr   = lane & 15;
    const int b    = w & 3;             // block within group
    const int h    = w >> 2;            // col-half: m in {2h, 2h+1}

    // ---- weights for block ngrp*4+b, col-half h -> 16 VGPRs (one-time) ----
    // frag (m,s): lane (g,lr) holds W[d = s*32+8g+i][e = (2h+m)*16+lr], i=0..7
    const float* Wn = blocks + (size_t)(ngrp * 4 + b) * 4096;
    short8 wf[2][2];
    #pragma unroll
    for (int m = 0; m < 2; ++m)
        #pragma unroll
        for (int s = 0; s < 2; ++s) {
            short8 a;
            #pragma unroll
            for (int i = 0; i < 8; ++i)
                a[i] = f2b(Wn[(s * 32 + 8 * g + i) * 64 + (2 * h + m) * 16 + lr]);
            wf[m][s] = a;
        }

    const float* gin  = inp + (size_t)slab * 512 * D_TOT + ngrp * 256;
    float*       gout = out + (size_t)slab * 512 * D_TOT + ngrp * 256;

    // ---- prologue: load + stage tile 0 into INB[0] (wave w: rows w, w+8) ----
    f32x4 pf[2];
    #pragma unroll
    for (int j = 0; j < 2; ++j)
        pf[j] = *(const f32x4*)(gin + (size_t)(w + 8 * j) * D_TOT + lane * 4);
    #pragma unroll
    for (int j = 0; j < 2; ++j) {
        const int r = w + 8 * j;
        bf16x4 v;
        v[0] = f2b(pf[j][0]); v[1] = f2b(pf[j][1]);
        v[2] = f2b(pf[j][2]); v[3] = f2b(pf[j][3]);
        *(bf16x4*)&INB[0][r * 512 + (((lane >> 1) ^ (r & 7)) << 4) + ((lane & 1) << 3)] = v;
    }
    __syncthreads();

    int c = 0;
    #pragma unroll 1
    for (int t = 0; t < NTILES; ++t) {
        // ---- 1. issue loads for tile t+1 (hidden under store+compute) ----
        if (t + 1 < NTILES) {
            const float* gi = gin + (size_t)(t + 1) * TROWS * D_TOT;
            #pragma unroll
            for (int j = 0; j < 2; ++j)
                pf[j] = *(const f32x4*)(gi + (size_t)(w + 8 * j) * D_TOT + lane * 4);
        }
        __builtin_amdgcn_sched_barrier(0);   // don't sink the loads

        // ---- 2. store tile t-1 from OUTB[c^1] (row-linear, NT, 1KB/instr) ----
        if (t > 0) {
            float* go = gout + (size_t)(t - 1) * TROWS * D_TOT;
            #pragma unroll
            for (int j = 0; j < 2; ++j) {
                const int r2 = w + 8 * j;
                f32x4 v = *(const f32x4*)&OUTB[c ^ 1][r2 * 1024 + ((lane ^ (r2 & 7)) << 4)];
                __builtin_nontemporal_store(v, (f32x4*)(go + (size_t)r2 * D_TOT + lane * 4));
            }
        }

        // ---- 3. compute tile t: b-frags from INB[c] (r = lr), 4 MFMA ----
        {
            const int r = lr;
            short8 bfrag[2];
            #pragma unroll
            for (int s = 0; s < 2; ++s) {
                const int cc = b * 8 + s * 4 + g;
                bfrag[s] = *(const short8*)&INB[c][r * 512 + ((cc ^ (r & 7)) << 4)];
            }
            #pragma unroll
            for (int m = 0; m < 2; ++m) {
                f32x4 acc = (f32x4){0.f, 0.f, 0.f, 0.f};
                acc = __builtin_amdgcn_mfma_f32_16x16x32_bf16(wf[m][0], bfrag[0], acc, 0, 0, 0);
                acc = __builtin_amdgcn_mfma_f32_16x16x32_bf16(wf[m][1], bfrag[1], acc, 0, 0, 0);
                const int cc = b * 16 + (2 * h + m) * 4 + g;   // 16B chunk 0..63
                *(f32x4*)&OUTB[c][r * 1024 + ((cc ^ (r & 7)) << 4)] = acc;
            }
        }

        // ---- 4. stage tile t+1 into INB[c^1] ----
        if (t + 1 < NTILES) {
            #pragma unroll
            for (int j = 0; j < 2; ++j) {
                const int r = w + 8 * j;
                bf16x4 v;
                v[0] = f2b(pf[j][0]); v[1] = f2b(pf[j][1]);
                v[2] = f2b(pf[j][2]); v[3] = f2b(pf[j][3]);
                *(bf16x4*)&INB[c ^ 1][r * 512 + (((lane >> 1) ^ (r & 7)) << 4) + ((lane & 1) << 3)] = v;
            }
        }

        __syncthreads();
        c ^= 1;
    }

    // ---- epilogue: store last tile from OUTB[c^1] ----
    {
        float* go = gout + (size_t)(NTILES - 1) * TROWS * D_TOT;
        #pragma unroll
        for (int j = 0; j < 2; ++j) {
            const int r2 = w + 8 * j;
            f32x4 v = *(const f32x4*)&OUTB[c ^ 1][r2 * 1024 + ((lane ^ (r2 & 7)) << 4)];
            __builtin_nontemporal_store(v, (f32x4*)(go + (size_t)r2 * D_TOT + lane * 4));
        }
    }
}

extern "C" void kernel_launch(void* const* d_in, const int* in_sizes, int n_in,
                              void* d_out, int out_size, void* d_ws, size_t ws_size,
                              hipStream_t stream) {
    const float* inp    = (const float*)d_in[0];
    const float* blocks = (const float*)d_in[1];
    float* out          = (float*)d_out;

    dim3 grid(32, 16);   // 32 row-slabs x 16 block-groups = 512 WGs (2/CU exact)
    block_linear_kernel<<<grid, 512, 0, stream>>>(inp, blocks, out);
}

// Round 15
// 88.315 us; speedup vs baseline: 1.1693x; 1.0245x over previous
//
#include <hip/hip_runtime.h>
#include <hip/hip_bf16.h>

// Block-diagonal matmul: out[t, n*64+e] = sum_d inp[t, n*64+d] * blocks[n, d, e]
// T=16384, 64 blocks of 64x64, fp32 in/out, bf16 MFMA compute.
//
// Round 15: R14 byte-identical EXCEPT stores use inline-asm
// "global_store_dwordx4 ... off sc0 sc1 nt" (full cache-bypass attempt).
// Theory: FETCH is pinned at 135.2MB (=50.4% of input) because the 262MB
// output stream still ALLOCATES in the Infinity Cache (builtin nt only
// bypasses L2), evicting half the near-resident 268MB input each replay.
// sc0+sc1+nt should make stores fully no-allocate -> input sole L3 occupant
// -> FETCH collapses -> physical bytes 407 -> ~300MB.
// Everything else identical to R14 (90.5us): double-buffered INB/OUTB, one
// barrier/tile, 1KB-contiguous bursts both ways, XOR-swizzled LDS bounce.

typedef __attribute__((ext_vector_type(8))) short short8;   // 8 bf16
typedef __attribute__((ext_vector_type(4))) short bf16x4;   // 4 bf16
typedef __attribute__((ext_vector_type(4))) float f32x4;

#define D_TOT  4096
#define TROWS  16
#define NTILES 32          // 512 rows per WG

__device__ __forceinline__ short f2b(float x) {
    union { __hip_bfloat16 h; short s; } u;
    u.h = __float2bfloat16(x);
    return u.s;
}

__device__ __forceinline__ void store_bypass(float* addr, f32x4 v) {
    asm volatile("global_store_dwordx4 %0, %1, off sc0 sc1 nt"
                 :: "v"(addr), "v"(v) : "memory");
}

__global__ __launch_bounds__(512, 4) void block_linear_kernel(
    const float* __restrict__ inp,
    const float* __restrict__ blocks,
    float* __restrict__ out)
{
    // double-buffered: INB 2x8KB (bf16 [16][256] swz), OUTB 2x16KB (f32 [16][256] swz)
    __shared__ __align__(16) unsigned char INB[2][TROWS * 512];
    __shared__ __align__(16) unsigned char OUTB[2][TROWS * 1024];

    const int slab = blockIdx.x;        // 0..31 : 512-row slab
    const int ngrp = blockIdx.y;        // 0..15 : group of 4 consecutive blocks
    const int tid  = threadIdx.x;
    const int w    = tid >> 6;          // wave 0..7
    const int lane = tid & 63;
    const int g    = lane >> 4;         // k-group
    const int lr   = lane & 15;
    const int b    = w & 3;             // block within group
    const int h    = w >> 2;            // col-half: m in {2h, 2h+1}

    // ---- weights for block ngrp*4+b, col-half h -> 16 VGPRs (one-time) ----
    // frag (m,s): lane (g,lr) holds W[d = s*32+8g+i][e = (2h+m)*16+lr], i=0..7
    const float* Wn = blocks + (size_t)(ngrp * 4 + b) * 4096;
    short8 wf[2][2];
    #pragma unroll
    for (int m = 0; m < 2; ++m)
        #pragma unroll
        for (int s = 0; s < 2; ++s) {
            short8 a;
            #pragma unroll
            for (int i = 0; i < 8; ++i)
                a[i] = f2b(Wn[(s * 32 + 8 * g + i) * 64 + (2 * h + m) * 16 + lr]);
            wf[m][s] = a;
        }

    const float* gin  = inp + (size_t)slab * 512 * D_TOT + ngrp * 256;
    float*       gout = out + (size_t)slab * 512 * D_TOT + ngrp * 256;

    // ---- prologue: load + stage tile 0 into INB[0] (wave w: rows w, w+8) ----
    f32x4 pf[2];
    #pragma unroll
    for (int j = 0; j < 2; ++j)
        pf[j] = *(const f32x4*)(gin + (size_t)(w + 8 * j) * D_TOT + lane * 4);
    #pragma unroll
    for (int j = 0; j < 2; ++j) {
        const int r = w + 8 * j;
        bf16x4 v;
        v[0] = f2b(pf[j][0]); v[1] = f2b(pf[j][1]);
        v[2] = f2b(pf[j][2]); v[3] = f2b(pf[j][3]);
        *(bf16x4*)&INB[0][r * 512 + (((lane >> 1) ^ (r & 7)) << 4) + ((lane & 1) << 3)] = v;
    }
    __syncthreads();

    int c = 0;
    #pragma unroll 1
    for (int t = 0; t < NTILES; ++t) {
        // ---- 1. issue loads for tile t+1 (hidden under store+compute) ----
        if (t + 1 < NTILES) {
            const float* gi = gin + (size_t)(t + 1) * TROWS * D_TOT;
            #pragma unroll
            for (int j = 0; j < 2; ++j)
                pf[j] = *(const f32x4*)(gi + (size_t)(w + 8 * j) * D_TOT + lane * 4);
        }
        __builtin_amdgcn_sched_barrier(0);   // don't sink the loads

        // ---- 2. store tile t-1 from OUTB[c^1] (row-linear, bypass, 1KB/instr) ----
        if (t > 0) {
            float* go = gout + (size_t)(t - 1) * TROWS * D_TOT;
            #pragma unroll
            for (int j = 0; j < 2; ++j) {
                const int r2 = w + 8 * j;
                f32x4 v = *(const f32x4*)&OUTB[c ^ 1][r2 * 1024 + ((lane ^ (r2 & 7)) << 4)];
                store_bypass(go + (size_t)r2 * D_TOT + lane * 4, v);
            }
        }

        // ---- 3. compute tile t: b-frags from INB[c] (r = lr), 4 MFMA ----
        {
            const int r = lr;
            short8 bfrag[2];
            #pragma unroll
            for (int s = 0; s < 2; ++s) {
                const int cc = b * 8 + s * 4 + g;
                bfrag[s] = *(const short8*)&INB[c][r * 512 + ((cc ^ (r & 7)) << 4)];
            }
            #pragma unroll
            for (int m = 0; m < 2; ++m) {
                f32x4 acc = (f32x4){0.f, 0.f, 0.f, 0.f};
                acc = __builtin_amdgcn_mfma_f32_16x16x32_bf16(wf[m][0], bfrag[0], acc, 0, 0, 0);
                acc = __builtin_amdgcn_mfma_f32_16x16x32_bf16(wf[m][1], bfrag[1], acc, 0, 0, 0);
                const int cc = b * 16 + (2 * h + m) * 4 + g;   // 16B chunk 0..63
                *(f32x4*)&OUTB[c][r * 1024 + ((cc ^ (r & 7)) << 4)] = acc;
            }
        }

        // ---- 4. stage tile t+1 into INB[c^1] ----
        if (t + 1 < NTILES) {
            #pragma unroll
            for (int j = 0; j < 2; ++j) {
                const int r = w + 8 * j;
                bf16x4 v;
                v[0] = f2b(pf[j][0]); v[1] = f2b(pf[j][1]);
                v[2] = f2b(pf[j][2]); v[3] = f2b(pf[j][3]);
                *(bf16x4*)&INB[c ^ 1][r * 512 + (((lane >> 1) ^ (r & 7)) << 4) + ((lane & 1) << 3)] = v;
            }
        }

        __syncthreads();
        c ^= 1;
    }

    // ---- epilogue: store last tile from OUTB[c^1] ----
    {
        float* go = gout + (size_t)(NTILES - 1) * TROWS * D_TOT;
        #pragma unroll
        for (int j = 0; j < 2; ++j) {
            const int r2 = w + 8 * j;
            f32x4 v = *(const f32x4*)&OUTB[c ^ 1][r2 * 1024 + ((lane ^ (r2 & 7)) << 4)];
            store_bypass(go + (size_t)r2 * D_TOT + lane * 4, v);
        }
    }
}

extern "C" void kernel_launch(void* const* d_in, const int* in_sizes, int n_in,
                              void* d_out, int out_size, void* d_ws, size_t ws_size,
                              hipStream_t stream) {
    const float* inp    = (const float*)d_in[0];
    const float* blocks = (const float*)d_in[1];
    float* out          = (float*)d_out;

    dim3 grid(32, 16);   // 32 row-slabs x 16 block-groups = 512 WGs (2/CU exact)
    block_linear_kernel<<<grid, 512, 0, stream>>>(inp, blocks, out);
}